// Round 3
// baseline (72.214 us; speedup 1.0000x reference)
//
#include <hip/hip_runtime.h>

#define DYN 16
#define DON 256
#define DIN 256
#define BSN 4096
#define NF 4096   /* DY*DI feature rows */
#define KTOT 512  /* concat K = 2*DI */

typedef unsigned short u16;
typedef __attribute__((ext_vector_type(8))) short bf16x8;
typedef __attribute__((ext_vector_type(4))) float f32x4;
typedef __attribute__((ext_vector_type(4))) unsigned short u16x4;

static __device__ __forceinline__ u16 f2bf(float f) {
  unsigned u = __builtin_bit_cast(unsigned, f);
  u += 0x7fffu + ((u >> 16) & 1u);
  return (u16)(u >> 16);
}
static __device__ __forceinline__ float bf2f(u16 h) {
  unsigned u = ((unsigned)h) << 16;
  return __builtin_bit_cast(float, u);
}

// ---------------------------------------------------------------------------
// Kernel 1: fold rms into weights, concat [Wu | Wl-with-reversed-rms] along K,
// convert to bf16. aprep layout: [4096 rows = d*256+o][512 k], k contiguous.
// ---------------------------------------------------------------------------
__global__ __launch_bounds__(256) void k_prep_w(
    const float* __restrict__ wu, const float* __restrict__ wl,
    const float* __restrict__ rms, u16* __restrict__ aprep) {
  int e = blockIdx.x * 256 + threadIdx.x;   // 262144 threads, 8 elems each
  int row = e >> 6;                         // 0..4095
  int k0 = (e & 63) << 3;                   // 0..504, step 8
  int d = row >> 8;
  const float* src;
  const float* rp;
  if (k0 < 256) {
    src = wu + (size_t)row * 256 + k0;
    rp  = rms + d * 256 + k0;
  } else {
    src = wl + (size_t)row * 256 + (k0 - 256);
    rp  = rms + (DYN - 1 - d) * 256 + (k0 - 256);
  }
  float4 s0 = *reinterpret_cast<const float4*>(src);
  float4 s1 = *reinterpret_cast<const float4*>(src + 4);
  float4 r0 = *reinterpret_cast<const float4*>(rp);
  float4 r1 = *reinterpret_cast<const float4*>(rp + 4);
  bf16x8 o;
  o[0] = (short)f2bf(s0.x * r0.x); o[1] = (short)f2bf(s0.y * r0.y);
  o[2] = (short)f2bf(s0.z * r0.z); o[3] = (short)f2bf(s0.w * r0.w);
  o[4] = (short)f2bf(s1.x * r1.x); o[5] = (short)f2bf(s1.y * r1.y);
  o[6] = (short)f2bf(s1.z * r1.z); o[7] = (short)f2bf(s1.w * r1.w);
  *reinterpret_cast<bf16x8*>(aprep + (size_t)row * KTOT + k0) = o;
}

// ---------------------------------------------------------------------------
// Kernel 2: 128x128 tiled transpose of x with f32->bf16 convert and per-column
// sum(x^2) partials. xbf layout: [BS rows = b][NF cols = f], f contiguous.
// partial layout: [32 f-tiles][BS].
// LDS read phase staggers j by chunk: 4-way banks instead of 16-way.
// ---------------------------------------------------------------------------
__global__ __launch_bounds__(256) void k_transpose(
    const float* __restrict__ x, u16* __restrict__ xbf,
    float* __restrict__ partial) {
  __shared__ u16 tile[128 * 132];  // [f][b], row stride 132 (264B): b64 writes ok
  const int t = threadIdx.x;
  const int bt = blockIdx.x, ft = blockIdx.y;
  const float* xb = x + (size_t)ft * 128 * BSN + bt * 128;
  const int frow = t >> 5, b4 = (t & 31) * 4;
  #pragma unroll
  for (int p = 0; p < 16; ++p) {
    int f = p * 8 + frow;
    float4 v = *reinterpret_cast<const float4*>(xb + (size_t)f * BSN + b4);
    u16x4 h;
    h[0] = f2bf(v.x); h[1] = f2bf(v.y); h[2] = f2bf(v.z); h[3] = f2bf(v.w);
    *reinterpret_cast<u16x4*>(&tile[f * 132 + b4]) = h;
  }
  __syncthreads();
  const int chunk = t & 15;  // f-octet index (lane&15 -> coalesced global write)
  const int bg = t >> 4;     // b row group
  #pragma unroll
  for (int p = 0; p < 8; ++p) {
    int b = bg + p * 16;
    float s = 0.f;
    bf16x8 w;
    #pragma unroll
    for (int jj = 0; jj < 8; ++jj) {
      int j = (jj + chunk) & 7;  // stagger: break same-column bank aliasing
      u16 v = tile[(chunk * 8 + j) * 132 + b];
      float xv = bf2f(v);
      s += xv * xv;
      w[j] = (short)v;
    }
    *reinterpret_cast<bf16x8*>(
        xbf + (size_t)(bt * 128 + b) * NF + ft * 128 + chunk * 8) = w;
    // reduce s across the 16 lanes sharing this b (chunk = lane&15)
    #pragma unroll
    for (int m = 1; m < 16; m <<= 1) s += __shfl_xor(s, m, 64);
    if (chunk == 0) partial[ft * BSN + bt * 128 + b] = s;
  }
}

// ---------------------------------------------------------------------------
// Kernel 3: fc[b] = rsqrt(mean(x^2) + eps)
// ---------------------------------------------------------------------------
__global__ __launch_bounds__(256) void k_fc(
    const float* __restrict__ partial, float* __restrict__ fc) {
  int b = blockIdx.x * 256 + threadIdx.x;
  float s = 0.f;
  #pragma unroll
  for (int i = 0; i < 32; ++i) s += partial[i * BSN + b];
  fc[b] = rsqrtf(s * (1.0f / 4096.0f) + 1e-6f);
}

// ---------------------------------------------------------------------------
// Kernel 4: bf16 MFMA GEMM, 128x128 tile per block.
// Flat grid 1024 with XCD-locality remap: xcd = bid&7 owns nt = xcd*4 +
// slot/32; the 32 blocks of one nt-group (mt 0/1 x d 0..15) are co-resident
// on ONE XCD, so the 4 blocks sharing each B-chunk (mt pair, d & 15-d pair)
// hit the same L2 (~200cy) instead of HBM (~900cy). Depth-1 prefetch + the
// CU's 4 resident blocks' MFMA (~310cy/SIMD/iter) then cover the latency.
// LDS tiles [128][32] bf16, byte XOR-swizzle phys = log ^ (((log>>7)&7)<<4)
// applied at pre-swizzled global source + ds_read (conflict-free, verified 0).
// Epilogue: relu(fc[col]*acc + bias[row]).
// ---------------------------------------------------------------------------
__global__ __launch_bounds__(256) void k_gemm(
    const u16* __restrict__ aprep, const u16* __restrict__ xbf,
    const float* __restrict__ fc, const float* __restrict__ bias,
    float* __restrict__ out) {
  __shared__ u16 As[2 * 4096];
  __shared__ u16 Bs[2 * 4096];
  const int bid = blockIdx.x;
  const int xcd = bid & 7, slot = bid >> 3;
  const int nt = (xcd << 2) | (slot >> 5);   // 4 nt-groups per XCD
  const int inner = slot & 31;
  const int mt = inner & 1, d = inner >> 1;
  const int t = threadIdx.x;
  const int wave = t >> 6, lane = t & 63;
  const int lhi = lane >> 4, llo = lane & 15;
  const int arow0 = d * 256 + mt * 128;
  const int bcol0 = nt * 128;
  const int wr = (wave >> 1) * 64, wc = (wave & 1) * 64;

  f32x4 acc[4][4] = {};

  auto stage = [&](int buf, int kt) {
    const int k0 = kt * 32;
    const int fb = (kt < 8) ? (d * 256 + k0) : ((DYN - 1 - d) * 256 + (k0 - 256));
    #pragma unroll
    for (int j = 0; j < 2; ++j) {
      int c = j * 256 + t;              // physical 16B chunk index (0..511)
      int cl = c ^ ((c >> 3) & 7);      // logical chunk (inverse swizzle)
      int r = cl >> 2, kg = cl & 3;     // logical row / k-octet
      const u16* ga = aprep + (size_t)(arow0 + r) * KTOT + k0 + kg * 8;
      const u16* gb = xbf + (size_t)(bcol0 + r) * NF + fb + kg * 8;
      unsigned lbase = (unsigned)((j * 256 + wave * 64) * 16);
      __builtin_amdgcn_global_load_lds(
          (const __attribute__((address_space(1))) unsigned int*)ga,
          (__attribute__((address_space(3))) unsigned int*)(
              (char*)&As[buf * 4096] + lbase), 16, 0, 0);
      __builtin_amdgcn_global_load_lds(
          (const __attribute__((address_space(1))) unsigned int*)gb,
          (__attribute__((address_space(3))) unsigned int*)(
              (char*)&Bs[buf * 4096] + lbase), 16, 0, 0);
    }
  };

  stage(0, 0);
  __syncthreads();

  for (int kt = 0; kt < 16; ++kt) {
    const int buf = kt & 1;
    if (kt < 15) stage(buf ^ 1, kt + 1);
    bf16x8 af[4], bq[4];
    #pragma unroll
    for (int m = 0; m < 4; ++m) {
      int rowa = wr + m * 16 + llo;
      int offa = (rowa * 64 + lhi * 16) ^ (((rowa >> 1) & 7) << 4);
      af[m] = *reinterpret_cast<const bf16x8*>(
          (const char*)&As[buf * 4096] + offa);
      int rowb = wc + m * 16 + llo;
      int offb = (rowb * 64 + lhi * 16) ^ (((rowb >> 1) & 7) << 4);
      bq[m] = *reinterpret_cast<const bf16x8*>(
          (const char*)&Bs[buf * 4096] + offb);
    }
    #pragma unroll
    for (int m = 0; m < 4; ++m)
      #pragma unroll
      for (int n = 0; n < 4; ++n)
        acc[m][n] = __builtin_amdgcn_mfma_f32_16x16x32_bf16(
            af[m], bq[n], acc[m][n], 0, 0, 0);
    __syncthreads();
  }

  // Epilogue: y = relu(fc[col] * acc + bias[row])
  #pragma unroll
  for (int m = 0; m < 4; ++m) {
    int row0 = arow0 + wr + m * 16 + lhi * 4;
    float bv[4];
    #pragma unroll
    for (int r = 0; r < 4; ++r) bv[r] = bias[row0 + r];
    #pragma unroll
    for (int n = 0; n < 4; ++n) {
      int col = bcol0 + wc + n * 16 + llo;
      float fcv = fc[col];
      #pragma unroll
      for (int r = 0; r < 4; ++r) {
        float v = acc[m][n][r] * fcv + bv[r];
        out[(size_t)(row0 + r) * BSN + col] = fmaxf(v, 0.f);
      }
    }
  }
}

extern "C" void kernel_launch(void* const* d_in, const int* in_sizes, int n_in,
                              void* d_out, int out_size, void* d_ws, size_t ws_size,
                              hipStream_t stream) {
  (void)in_sizes; (void)n_in; (void)out_size; (void)ws_size;
  const float* x    = (const float*)d_in[0];
  const float* rms  = (const float*)d_in[1];
  const float* wu   = (const float*)d_in[2];
  const float* wl   = (const float*)d_in[3];
  const float* bias = (const float*)d_in[4];
  float* out = (float*)d_out;

  char* ws = (char*)d_ws;
  u16* xbf      = (u16*)ws;                      // 32 MiB  (x^T bf16)
  u16* aprep    = (u16*)(ws + 33554432);         // 4 MiB   (folded weights)
  float* partial = (float*)(ws + 37748736);      // 512 KiB (sumsq partials)
  float* fc      = (float*)(ws + 38273024);      // 16 KiB

  k_prep_w<<<1024, 256, 0, stream>>>(wu, wl, rms, aprep);
  k_transpose<<<dim3(32, 32), 256, 0, stream>>>(x, xbf, partial);
  k_fc<<<16, 256, 0, stream>>>(partial, fc);
  k_gemm<<<1024, 256, 0, stream>>>(aprep, xbf, fc, bias, out);
}

// Round 5
// 60.826 us; speedup vs baseline: 1.1872x; 1.1872x over previous
//
#include <hip/hip_runtime.h>

#define DYN 16
#define DON 256
#define DIN 256
#define BSN 4096
#define NF 4096   /* DY*DI feature rows */
#define KTOT 512  /* concat K = 2*DI */

typedef unsigned short u16;
typedef __attribute__((ext_vector_type(8))) short bf16x8;
typedef __attribute__((ext_vector_type(4))) float f32x4;
typedef __attribute__((ext_vector_type(4))) unsigned short u16x4;

static __device__ __forceinline__ u16 f2bf(float f) {
  unsigned u = __builtin_bit_cast(unsigned, f);
  u += 0x7fffu + ((u >> 16) & 1u);
  return (u16)(u >> 16);
}
static __device__ __forceinline__ float bf2f(u16 h) {
  unsigned u = ((unsigned)h) << 16;
  return __builtin_bit_cast(float, u);
}

// ---------------------------------------------------------------------------
// Kernel 1: fold rms into weights, concat [Wu | Wl-with-reversed-rms] along K,
// convert to bf16. aprep layout: [4096 rows = d*256+o][512 k], k contiguous.
// ---------------------------------------------------------------------------
__global__ __launch_bounds__(256) void k_prep_w(
    const float* __restrict__ wu, const float* __restrict__ wl,
    const float* __restrict__ rms, u16* __restrict__ aprep) {
  int e = blockIdx.x * 256 + threadIdx.x;   // 262144 threads, 8 elems each
  int row = e >> 6;                         // 0..4095
  int k0 = (e & 63) << 3;                   // 0..504, step 8
  int d = row >> 8;
  const float* src;
  const float* rp;
  if (k0 < 256) {
    src = wu + (size_t)row * 256 + k0;
    rp  = rms + d * 256 + k0;
  } else {
    src = wl + (size_t)row * 256 + (k0 - 256);
    rp  = rms + (DYN - 1 - d) * 256 + (k0 - 256);
  }
  float4 s0 = *reinterpret_cast<const float4*>(src);
  float4 s1 = *reinterpret_cast<const float4*>(src + 4);
  float4 r0 = *reinterpret_cast<const float4*>(rp);
  float4 r1 = *reinterpret_cast<const float4*>(rp + 4);
  bf16x8 o;
  o[0] = (short)f2bf(s0.x * r0.x); o[1] = (short)f2bf(s0.y * r0.y);
  o[2] = (short)f2bf(s0.z * r0.z); o[3] = (short)f2bf(s0.w * r0.w);
  o[4] = (short)f2bf(s1.x * r1.x); o[5] = (short)f2bf(s1.y * r1.y);
  o[6] = (short)f2bf(s1.z * r1.z); o[7] = (short)f2bf(s1.w * r1.w);
  *reinterpret_cast<bf16x8*>(aprep + (size_t)row * KTOT + k0) = o;
}

// ---------------------------------------------------------------------------
// Kernel 2: 128x128 tiled transpose of x with f32->bf16 convert and per-column
// sum(x^2) partials. xbf layout: [BS rows = b][NF cols = f], f contiguous.
// ---------------------------------------------------------------------------
__global__ __launch_bounds__(256) void k_transpose(
    const float* __restrict__ x, u16* __restrict__ xbf,
    float* __restrict__ partial) {
  __shared__ u16 tile[128 * 132];  // [f][b], row stride 132 (264B)
  const int t = threadIdx.x;
  const int bt = blockIdx.x, ft = blockIdx.y;
  const float* xb = x + (size_t)ft * 128 * BSN + bt * 128;
  const int frow = t >> 5, b4 = (t & 31) * 4;
  #pragma unroll
  for (int p = 0; p < 16; ++p) {
    int f = p * 8 + frow;
    float4 v = *reinterpret_cast<const float4*>(xb + (size_t)f * BSN + b4);
    u16x4 h;
    h[0] = f2bf(v.x); h[1] = f2bf(v.y); h[2] = f2bf(v.z); h[3] = f2bf(v.w);
    *reinterpret_cast<u16x4*>(&tile[f * 132 + b4]) = h;
  }
  __syncthreads();
  const int chunk = t & 15;
  const int bg = t >> 4;
  #pragma unroll
  for (int p = 0; p < 8; ++p) {
    int b = bg + p * 16;
    float s = 0.f;
    bf16x8 w;
    #pragma unroll
    for (int jj = 0; jj < 8; ++jj) {
      int j = (jj + chunk) & 7;  // stagger: break same-column bank aliasing
      u16 v = tile[(chunk * 8 + j) * 132 + b];
      float xv = bf2f(v);
      s += xv * xv;
      w[j] = (short)v;
    }
    *reinterpret_cast<bf16x8*>(
        xbf + (size_t)(bt * 128 + b) * NF + ft * 128 + chunk * 8) = w;
    #pragma unroll
    for (int m = 1; m < 16; m <<= 1) s += __shfl_xor(s, m, 64);
    if (chunk == 0) partial[ft * BSN + bt * 128 + b] = s;
  }
}

// ---------------------------------------------------------------------------
// Kernel 3: fc[b] = rsqrt(mean(x^2) + eps)
// ---------------------------------------------------------------------------
__global__ __launch_bounds__(256) void k_fc(
    const float* __restrict__ partial, float* __restrict__ fc) {
  int b = blockIdx.x * 256 + threadIdx.x;
  float s = 0.f;
  #pragma unroll
  for (int i = 0; i < 32; ++i) s += partial[i * BSN + b];
  fc[b] = rsqrtf(s * (1.0f / 4096.0f) + 1e-6f);
}

// ---------------------------------------------------------------------------
// Kernel 4: bf16 MFMA GEMM, 256x256 tile, BK=32, 8 waves (2M x 4N), 1 blk/CU.
// T3/T4 minimum-2-phase: per iter {STAGE(t+1); ds_read+MFMA(t); vmcnt(0)+
// barrier} - the counted wait lands AFTER ~600cy of MFMA covering the load
// latency, vs __syncthreads' immediate vmcnt(0) drain (the m97 20% stall).
// Block map: pair {d, 15-d} (identical B bytes) on same XCD via bid%8;
// per-XCD working set = 4.5MB ~ L2.
// LDS [256 rows][32 k] bf16 per operand, stride 64B, involution swizzle
// byte ^ (((byte>>7)&7)<<4) at pre-swizzled global source + ds_read
// (identical math to R2's measured-zero-conflict kernel).
// Epilogue: relu(fc[col]*acc + bias[row]).
// ---------------------------------------------------------------------------
__global__ __launch_bounds__(512, 2) void k_gemm(
    const u16* __restrict__ aprep, const u16* __restrict__ xbf,
    const float* __restrict__ fc, const float* __restrict__ bias,
    float* __restrict__ out) {
  __shared__ u16 As[2 * 8192];   // 2 buf x 256x32
  __shared__ u16 Bs[2 * 8192];
  const int bid = blockIdx.x;
  const int xcd = bid & 7, w = bid >> 3;
  const int d = (w & 1) ? (15 - xcd) : xcd;   // d-pair co-resident on one XCD
  const int nt = w >> 1;                       // 0..15
  const int t = threadIdx.x;
  const int wave = t >> 6, lane = t & 63;
  const int lhi = lane >> 4, llo = lane & 15;
  const int wm = wave >> 2, wn = wave & 3;     // 2M x 4N wave grid
  const int arow0 = d * 256;
  const int bcol0 = nt * 256;

  f32x4 acc[8][4] = {};

  auto stage = [&](int buf, int kt) {
    const int fbase = (kt < 8) ? (d * 256 + kt * 32)
                               : ((DYN - 1 - d) * 256 + (kt - 8) * 32);
    #pragma unroll
    for (int j = 0; j < 2; ++j) {
      int c = j * 512 + t;              // physical 16B chunk index (0..1023)
      int cl = c ^ ((c >> 3) & 7);      // logical chunk (involution)
      int r = cl >> 2, kc = cl & 3;     // logical row / k-octet
      const u16* ga = aprep + (size_t)(arow0 + r) * KTOT + kt * 32 + kc * 8;
      const u16* gb = xbf + (size_t)(bcol0 + r) * NF + fbase + kc * 8;
      unsigned lbase = (unsigned)((j * 512 + wave * 64) * 16);
      __builtin_amdgcn_global_load_lds(
          (const __attribute__((address_space(1))) unsigned int*)ga,
          (__attribute__((address_space(3))) unsigned int*)(
              (char*)&As[buf * 8192] + lbase), 16, 0, 0);
      __builtin_amdgcn_global_load_lds(
          (const __attribute__((address_space(1))) unsigned int*)gb,
          (__attribute__((address_space(3))) unsigned int*)(
              (char*)&Bs[buf * 8192] + lbase), 16, 0, 0);
    }
  };

  const int kmask = ((llo >> 1) & 7) << 4;   // thread-constant swizzle mask

  stage(0, 0);
  asm volatile("s_waitcnt vmcnt(0)\n\ts_barrier" ::: "memory");

  for (int kt = 0; kt < 16; ++kt) {
    const int buf = kt & 1;
    if (kt < 15) stage(buf ^ 1, kt + 1);

    bf16x8 af[8], bq[4];
    #pragma unroll
    for (int m = 0; m < 8; ++m) {
      int rowa = wm * 128 + m * 16 + llo;
      int offa = (rowa * 64 + lhi * 16) ^ kmask;
      af[m] = *reinterpret_cast<const bf16x8*>(
          (const char*)&As[buf * 8192] + offa);
    }
    #pragma unroll
    for (int n = 0; n < 4; ++n) {
      int rowb = wn * 64 + n * 16 + llo;
      int offb = (rowb * 64 + lhi * 16) ^ kmask;
      bq[n] = *reinterpret_cast<const bf16x8*>(
          (const char*)&Bs[buf * 8192] + offb);
    }
    __builtin_amdgcn_s_setprio(1);
    #pragma unroll
    for (int m = 0; m < 8; ++m)
      #pragma unroll
      for (int n = 0; n < 4; ++n)
        acc[m][n] = __builtin_amdgcn_mfma_f32_16x16x32_bf16(
            af[m], bq[n], acc[m][n], 0, 0, 0);
    __builtin_amdgcn_s_setprio(0);

    if (kt < 15)
      asm volatile("s_waitcnt vmcnt(0)\n\ts_barrier" ::: "memory");
  }

  // Epilogue: y = relu(fc[col] * acc + bias[row])
  float fcv[4];
  #pragma unroll
  for (int n = 0; n < 4; ++n) fcv[n] = fc[bcol0 + wn * 64 + n * 16 + llo];
  #pragma unroll
  for (int m = 0; m < 8; ++m) {
    int row0 = arow0 + wm * 128 + m * 16 + lhi * 4;
    float bv[4];
    #pragma unroll
    for (int r = 0; r < 4; ++r) bv[r] = bias[row0 + r];
    #pragma unroll
    for (int n = 0; n < 4; ++n) {
      int col = bcol0 + wn * 64 + n * 16 + llo;
      #pragma unroll
      for (int r = 0; r < 4; ++r) {
        float v = acc[m][n][r] * fcv[n] + bv[r];
        out[(size_t)(row0 + r) * BSN + col] = fmaxf(v, 0.f);
      }
    }
  }
}

extern "C" void kernel_launch(void* const* d_in, const int* in_sizes, int n_in,
                              void* d_out, int out_size, void* d_ws, size_t ws_size,
                              hipStream_t stream) {
  (void)in_sizes; (void)n_in; (void)out_size; (void)ws_size;
  const float* x    = (const float*)d_in[0];
  const float* rms  = (const float*)d_in[1];
  const float* wu   = (const float*)d_in[2];
  const float* wl   = (const float*)d_in[3];
  const float* bias = (const float*)d_in[4];
  float* out = (float*)d_out;

  char* ws = (char*)d_ws;
  u16* xbf      = (u16*)ws;                      // 32 MiB  (x^T bf16)
  u16* aprep    = (u16*)(ws + 33554432);         // 4 MiB   (folded weights)
  float* partial = (float*)(ws + 37748736);      // 512 KiB (sumsq partials)
  float* fc      = (float*)(ws + 38273024);      // 16 KiB

  k_prep_w<<<1024, 256, 0, stream>>>(wu, wl, rms, aprep);
  k_transpose<<<dim3(32, 32), 256, 0, stream>>>(x, xbf, partial);
  k_fc<<<16, 256, 0, stream>>>(partial, fc);
  k_gemm<<<256, 512, 0, stream>>>(aprep, xbf, fc, bias, out);
}

// Round 6
// 59.702 us; speedup vs baseline: 1.2096x; 1.0188x over previous
//
#include <hip/hip_runtime.h>

#define DYN 16
#define DON 256
#define DIN 256
#define BSN 4096
#define NF 4096   /* DY*DI feature rows */
#define KTOT 512  /* concat K = 2*DI */

typedef unsigned short u16;
typedef __attribute__((ext_vector_type(8))) short bf16x8;
typedef __attribute__((ext_vector_type(4))) float f32x4;
typedef __attribute__((ext_vector_type(4))) unsigned short u16x4;

static __device__ __forceinline__ u16 f2bf(float f) {
  unsigned u = __builtin_bit_cast(unsigned, f);
  u += 0x7fffu + ((u >> 16) & 1u);
  return (u16)(u >> 16);
}
static __device__ __forceinline__ float bf2f(u16 h) {
  unsigned u = ((unsigned)h) << 16;
  return __builtin_bit_cast(float, u);
}

// ---------------------------------------------------------------------------
// Kernel 1: fold rms into weights, concat [Wu | Wl-with-reversed-rms] along K,
// convert to bf16. aprep layout: [4096 rows = d*256+o][512 k], k contiguous.
// ---------------------------------------------------------------------------
__global__ __launch_bounds__(256) void k_prep_w(
    const float* __restrict__ wu, const float* __restrict__ wl,
    const float* __restrict__ rms, u16* __restrict__ aprep) {
  int e = blockIdx.x * 256 + threadIdx.x;   // 262144 threads, 8 elems each
  int row = e >> 6;                         // 0..4095
  int k0 = (e & 63) << 3;                   // 0..504, step 8
  int d = row >> 8;
  const float* src;
  const float* rp;
  if (k0 < 256) {
    src = wu + (size_t)row * 256 + k0;
    rp  = rms + d * 256 + k0;
  } else {
    src = wl + (size_t)row * 256 + (k0 - 256);
    rp  = rms + (DYN - 1 - d) * 256 + (k0 - 256);
  }
  float4 s0 = *reinterpret_cast<const float4*>(src);
  float4 s1 = *reinterpret_cast<const float4*>(src + 4);
  float4 r0 = *reinterpret_cast<const float4*>(rp);
  float4 r1 = *reinterpret_cast<const float4*>(rp + 4);
  bf16x8 o;
  o[0] = (short)f2bf(s0.x * r0.x); o[1] = (short)f2bf(s0.y * r0.y);
  o[2] = (short)f2bf(s0.z * r0.z); o[3] = (short)f2bf(s0.w * r0.w);
  o[4] = (short)f2bf(s1.x * r1.x); o[5] = (short)f2bf(s1.y * r1.y);
  o[6] = (short)f2bf(s1.z * r1.z); o[7] = (short)f2bf(s1.w * r1.w);
  *reinterpret_cast<bf16x8*>(aprep + (size_t)row * KTOT + k0) = o;
}

// ---------------------------------------------------------------------------
// Kernel 2: 128x128 tiled transpose of x with f32->bf16 convert and per-column
// sum(x^2) partials. xbf layout: [BS rows = b][NF cols = f], f contiguous.
// ---------------------------------------------------------------------------
__global__ __launch_bounds__(256) void k_transpose(
    const float* __restrict__ x, u16* __restrict__ xbf,
    float* __restrict__ partial) {
  __shared__ u16 tile[128 * 132];  // [f][b], row stride 132 (264B)
  const int t = threadIdx.x;
  const int bt = blockIdx.x, ft = blockIdx.y;
  const float* xb = x + (size_t)ft * 128 * BSN + bt * 128;
  const int frow = t >> 5, b4 = (t & 31) * 4;
  #pragma unroll
  for (int p = 0; p < 16; ++p) {
    int f = p * 8 + frow;
    float4 v = *reinterpret_cast<const float4*>(xb + (size_t)f * BSN + b4);
    u16x4 h;
    h[0] = f2bf(v.x); h[1] = f2bf(v.y); h[2] = f2bf(v.z); h[3] = f2bf(v.w);
    *reinterpret_cast<u16x4*>(&tile[f * 132 + b4]) = h;
  }
  __syncthreads();
  const int chunk = t & 15;
  const int bg = t >> 4;
  #pragma unroll
  for (int p = 0; p < 8; ++p) {
    int b = bg + p * 16;
    float s = 0.f;
    bf16x8 w;
    #pragma unroll
    for (int jj = 0; jj < 8; ++jj) {
      int j = (jj + chunk) & 7;  // stagger: break same-column bank aliasing
      u16 v = tile[(chunk * 8 + j) * 132 + b];
      float xv = bf2f(v);
      s += xv * xv;
      w[j] = (short)v;
    }
    *reinterpret_cast<bf16x8*>(
        xbf + (size_t)(bt * 128 + b) * NF + ft * 128 + chunk * 8) = w;
    #pragma unroll
    for (int m = 1; m < 16; m <<= 1) s += __shfl_xor(s, m, 64);
    if (chunk == 0) partial[ft * BSN + bt * 128 + b] = s;
  }
}

// ---------------------------------------------------------------------------
// Kernel 3: fc[b] = rsqrt(mean(x^2) + eps)
// ---------------------------------------------------------------------------
__global__ __launch_bounds__(256) void k_fc(
    const float* __restrict__ partial, float* __restrict__ fc) {
  int b = blockIdx.x * 256 + threadIdx.x;
  float s = 0.f;
  #pragma unroll
  for (int i = 0; i < 32; ++i) s += partial[i * BSN + b];
  fc[b] = rsqrtf(s * (1.0f / 4096.0f) + 1e-6f);
}

// ---------------------------------------------------------------------------
// Kernel 4: bf16 MFMA GEMM, 256x256 tile, BK=32, 8 waves (2M x 4N), 1 blk/CU.
// T3/T4 with REAL pipeline depth 2: 3-slot LDS ring, steady-state
// s_waitcnt vmcnt(4) (4 loads/thread/stage; 2 stages in flight = 8
// outstanding; waiting the oldest 4 completes stage kt+1 while stage kt+2
// rides across the barrier). Loads never drain to 0 until the tail (m218's
// counted-vs-drain0 lever, +38-73%). WAR safe: a wave's ds_reads of slot s
// complete before its MFMAs (lgkm) hence before the barrier; the overwrite
// of s is issued only after that barrier.
// LDS 96KB dynamic (3 x 16KB per operand), 1 blk/CU.
// Block map: pair {d, 15-d} (identical B bytes) on same XCD via bid%8.
// Involution swizzle byte ^ (((byte>>7)&7)<<4) at pre-swizzled global source
// + ds_read (measured-zero-conflict math from R2, unchanged).
// Epilogue: relu(fc[col]*acc + bias[row]).
// ---------------------------------------------------------------------------
__global__ __launch_bounds__(512, 2) void k_gemm(
    const u16* __restrict__ aprep, const u16* __restrict__ xbf,
    const float* __restrict__ fc, const float* __restrict__ bias,
    float* __restrict__ out) {
  extern __shared__ u16 lds[];
  u16* As = lds;              // 3 slots x 8192 u16
  u16* Bs = lds + 3 * 8192;   // 3 slots x 8192 u16
  const int bid = blockIdx.x;
  const int xcd = bid & 7, w = bid >> 3;
  const int d = (w & 1) ? (15 - xcd) : xcd;   // d-pair co-resident on one XCD
  const int nt = w >> 1;                       // 0..15
  const int t = threadIdx.x;
  const int wave = t >> 6, lane = t & 63;
  const int lhi = lane >> 4, llo = lane & 15;
  const int wm = wave >> 2, wn = wave & 3;     // 2M x 4N wave grid
  const int arow0 = d * 256;
  const int bcol0 = nt * 256;

  f32x4 acc[8][4] = {};

  auto stage = [&](int slot, int kt) {
    const int fbase = (kt < 8) ? (d * 256 + kt * 32)
                               : ((DYN - 1 - d) * 256 + (kt - 8) * 32);
    #pragma unroll
    for (int j = 0; j < 2; ++j) {
      int c = j * 512 + t;              // physical 16B chunk index (0..1023)
      int cl = c ^ ((c >> 3) & 7);      // logical chunk (involution)
      int r = cl >> 2, kc = cl & 3;     // logical row / k-octet
      const u16* ga = aprep + (size_t)(arow0 + r) * KTOT + kt * 32 + kc * 8;
      const u16* gb = xbf + (size_t)(bcol0 + r) * NF + fbase + kc * 8;
      unsigned lbase = (unsigned)((j * 512 + wave * 64) * 16);
      __builtin_amdgcn_global_load_lds(
          (const __attribute__((address_space(1))) unsigned int*)ga,
          (__attribute__((address_space(3))) unsigned int*)(
              (char*)&As[slot * 8192] + lbase), 16, 0, 0);
      __builtin_amdgcn_global_load_lds(
          (const __attribute__((address_space(1))) unsigned int*)gb,
          (__attribute__((address_space(3))) unsigned int*)(
              (char*)&Bs[slot * 8192] + lbase), 16, 0, 0);
    }
  };

  const int kmask = ((llo >> 1) & 7) << 4;   // thread-constant swizzle mask

  stage(0, 0);
  stage(1, 1);
  asm volatile("s_waitcnt vmcnt(4)\n\ts_barrier" ::: "memory");

  for (int kt = 0; kt < 16; ++kt) {
    const int slot = kt % 3;
    if (kt < 14) stage((kt + 2) % 3, kt + 2);

    bf16x8 af[8], bq[4];
    #pragma unroll
    for (int m = 0; m < 8; ++m) {
      int rowa = wm * 128 + m * 16 + llo;
      int offa = (rowa * 64 + lhi * 16) ^ kmask;
      af[m] = *reinterpret_cast<const bf16x8*>(
          (const char*)&As[slot * 8192] + offa);
    }
    #pragma unroll
    for (int n = 0; n < 4; ++n) {
      int rowb = wn * 64 + n * 16 + llo;
      int offb = (rowb * 64 + lhi * 16) ^ kmask;
      bq[n] = *reinterpret_cast<const bf16x8*>(
          (const char*)&Bs[slot * 8192] + offb);
    }
    __builtin_amdgcn_s_setprio(1);
    #pragma unroll
    for (int m = 0; m < 8; ++m)
      #pragma unroll
      for (int n = 0; n < 4; ++n)
        acc[m][n] = __builtin_amdgcn_mfma_f32_16x16x32_bf16(
            af[m], bq[n], acc[m][n], 0, 0, 0);
    __builtin_amdgcn_s_setprio(0);

    if (kt < 14) {
      asm volatile("s_waitcnt vmcnt(4)\n\ts_barrier" ::: "memory");
    } else if (kt == 14) {
      asm volatile("s_waitcnt vmcnt(0)\n\ts_barrier" ::: "memory");
    }
  }

  // Epilogue: y = relu(fc[col] * acc + bias[row])
  float fcv[4];
  #pragma unroll
  for (int n = 0; n < 4; ++n) fcv[n] = fc[bcol0 + wn * 64 + n * 16 + llo];
  #pragma unroll
  for (int m = 0; m < 8; ++m) {
    int row0 = arow0 + wm * 128 + m * 16 + lhi * 4;
    float bv[4];
    #pragma unroll
    for (int r = 0; r < 4; ++r) bv[r] = bias[row0 + r];
    #pragma unroll
    for (int n = 0; n < 4; ++n) {
      int col = bcol0 + wn * 64 + n * 16 + llo;
      #pragma unroll
      for (int r = 0; r < 4; ++r) {
        float v = acc[m][n][r] * fcv[n] + bv[r];
        out[(size_t)(row0 + r) * BSN + col] = fmaxf(v, 0.f);
      }
    }
  }
}

extern "C" void kernel_launch(void* const* d_in, const int* in_sizes, int n_in,
                              void* d_out, int out_size, void* d_ws, size_t ws_size,
                              hipStream_t stream) {
  (void)in_sizes; (void)n_in; (void)out_size; (void)ws_size;
  const float* x    = (const float*)d_in[0];
  const float* rms  = (const float*)d_in[1];
  const float* wu   = (const float*)d_in[2];
  const float* wl   = (const float*)d_in[3];
  const float* bias = (const float*)d_in[4];
  float* out = (float*)d_out;

  char* ws = (char*)d_ws;
  u16* xbf      = (u16*)ws;                      // 32 MiB  (x^T bf16)
  u16* aprep    = (u16*)(ws + 33554432);         // 4 MiB   (folded weights)
  float* partial = (float*)(ws + 37748736);      // 512 KiB (sumsq partials)
  float* fc      = (float*)(ws + 38273024);      // 16 KiB

  k_prep_w<<<1024, 256, 0, stream>>>(wu, wl, rms, aprep);
  k_transpose<<<dim3(32, 32), 256, 0, stream>>>(x, xbf, partial);
  k_fc<<<16, 256, 0, stream>>>(partial, fc);
  k_gemm<<<256, 512, 98304, stream>>>(aprep, xbf, fc, bias, out);
}

// Round 7
// 57.871 us; speedup vs baseline: 1.2479x; 1.0316x over previous
//
#include <hip/hip_runtime.h>

#define DYN 16
#define DON 256
#define DIN 256
#define BSN 4096
#define NF 4096   /* DY*DI feature rows */
#define KTOT 512  /* concat K = 2*DI */

typedef unsigned short u16;
typedef __attribute__((ext_vector_type(8))) short bf16x8;
typedef __attribute__((ext_vector_type(4))) float f32x4;
typedef __attribute__((ext_vector_type(4))) unsigned short u16x4;

static __device__ __forceinline__ u16 f2bf(float f) {
  unsigned u = __builtin_bit_cast(unsigned, f);
  u += 0x7fffu + ((u >> 16) & 1u);
  return (u16)(u >> 16);
}
static __device__ __forceinline__ float bf2f(u16 h) {
  unsigned u = ((unsigned)h) << 16;
  return __builtin_bit_cast(float, u);
}

// ---------------------------------------------------------------------------
// Kernel 1: fold rms into weights, concat [Wu | Wl-with-reversed-rms] along K,
// convert to bf16. aprep layout: [4096 rows = d*256+o][512 k], k contiguous.
// ---------------------------------------------------------------------------
__global__ __launch_bounds__(256) void k_prep_w(
    const float* __restrict__ wu, const float* __restrict__ wl,
    const float* __restrict__ rms, u16* __restrict__ aprep) {
  int e = blockIdx.x * 256 + threadIdx.x;   // 262144 threads, 8 elems each
  int row = e >> 6;                         // 0..4095
  int k0 = (e & 63) << 3;                   // 0..504, step 8
  int d = row >> 8;
  const float* src;
  const float* rp;
  if (k0 < 256) {
    src = wu + (size_t)row * 256 + k0;
    rp  = rms + d * 256 + k0;
  } else {
    src = wl + (size_t)row * 256 + (k0 - 256);
    rp  = rms + (DYN - 1 - d) * 256 + (k0 - 256);
  }
  float4 s0 = *reinterpret_cast<const float4*>(src);
  float4 s1 = *reinterpret_cast<const float4*>(src + 4);
  float4 r0 = *reinterpret_cast<const float4*>(rp);
  float4 r1 = *reinterpret_cast<const float4*>(rp + 4);
  bf16x8 o;
  o[0] = (short)f2bf(s0.x * r0.x); o[1] = (short)f2bf(s0.y * r0.y);
  o[2] = (short)f2bf(s0.z * r0.z); o[3] = (short)f2bf(s0.w * r0.w);
  o[4] = (short)f2bf(s1.x * r1.x); o[5] = (short)f2bf(s1.y * r1.y);
  o[6] = (short)f2bf(s1.z * r1.z); o[7] = (short)f2bf(s1.w * r1.w);
  *reinterpret_cast<bf16x8*>(aprep + (size_t)row * KTOT + k0) = o;
}

// ---------------------------------------------------------------------------
// Kernel 2: 128x128 tiled transpose of x with f32->bf16 convert and per-column
// sum(x^2) partials. xbf layout: [BS rows = b][NF cols = f], f contiguous.
// ---------------------------------------------------------------------------
__global__ __launch_bounds__(256) void k_transpose(
    const float* __restrict__ x, u16* __restrict__ xbf,
    float* __restrict__ partial) {
  __shared__ u16 tile[128 * 132];  // [f][b], row stride 132 (264B)
  const int t = threadIdx.x;
  const int bt = blockIdx.x, ft = blockIdx.y;
  const float* xb = x + (size_t)ft * 128 * BSN + bt * 128;
  const int frow = t >> 5, b4 = (t & 31) * 4;
  #pragma unroll
  for (int p = 0; p < 16; ++p) {
    int f = p * 8 + frow;
    float4 v = *reinterpret_cast<const float4*>(xb + (size_t)f * BSN + b4);
    u16x4 h;
    h[0] = f2bf(v.x); h[1] = f2bf(v.y); h[2] = f2bf(v.z); h[3] = f2bf(v.w);
    *reinterpret_cast<u16x4*>(&tile[f * 132 + b4]) = h;
  }
  __syncthreads();
  const int chunk = t & 15;
  const int bg = t >> 4;
  #pragma unroll
  for (int p = 0; p < 8; ++p) {
    int b = bg + p * 16;
    float s = 0.f;
    bf16x8 w;
    #pragma unroll
    for (int jj = 0; jj < 8; ++jj) {
      int j = (jj + chunk) & 7;  // stagger: break same-column bank aliasing
      u16 v = tile[(chunk * 8 + j) * 132 + b];
      float xv = bf2f(v);
      s += xv * xv;
      w[j] = (short)v;
    }
    *reinterpret_cast<bf16x8*>(
        xbf + (size_t)(bt * 128 + b) * NF + ft * 128 + chunk * 8) = w;
    #pragma unroll
    for (int m = 1; m < 16; m <<= 1) s += __shfl_xor(s, m, 64);
    if (chunk == 0) partial[ft * BSN + bt * 128 + b] = s;
  }
}

// ---------------------------------------------------------------------------
// Kernel 3: bf16 MFMA GEMM, 128x128 tile, BK=32, 4 waves (2M x 2N),
// 3 blocks/CU (m97's measured-good occupancy regime: cross-block overlap
// covers barrier stalls - m114). 3-slot LDS ring, steady s_waitcnt vmcnt(4)
// (4 loads/thread/stage, 2 stages in flight; loads never drain to 0 until
// the tail). fc = rsqrt(mean(x^2)+eps) folded into the prologue: reduce
// partial[32][128 cols] into LDS while stages 0/1 are in flight (k_fc
// kernel eliminated).
// Block map: bid&7 = xcd; d in {x,15-x} so the d-pair (identical B bytes)
// and all nt/mt (A reuse x64) are co-resident per XCD.
// Involution swizzle byte ^ (((byte>>7)&7)<<4) at pre-swizzled global source
// + ds_read (R2 measured-zero-conflict math, unchanged).
// Epilogue: relu(fc[col]*acc + bias[row]).
// ---------------------------------------------------------------------------
__global__ __launch_bounds__(256, 3) void k_gemm(
    const u16* __restrict__ aprep, const u16* __restrict__ xbf,
    const float* __restrict__ partial, const float* __restrict__ bias,
    float* __restrict__ out) {
  extern __shared__ char smem[];
  float* fcl = (float*)smem;                 // 128 floats
  u16* As = (u16*)(smem + 512);              // 3 slots x 4096 u16 (128x32)
  u16* Bs = As + 3 * 4096;                   // 3 slots x 4096 u16
  const int bid = blockIdx.x;
  const int x8 = bid & 7, s = bid >> 3;      // s in 0..127
  const int d = (s & 1) ? (15 - x8) : x8;    // d-pair co-resident on one XCD
  const int mt = (s >> 1) & 1;
  const int nt = s >> 2;                     // 0..31
  const int t = threadIdx.x;
  const int wave = t >> 6, lane = t & 63;
  const int lhi = lane >> 4, llo = lane & 15;
  const int wm = wave >> 1, wn = wave & 1;   // 2M x 2N wave grid, 64x64 each
  const int arow0 = d * 256 + mt * 128;
  const int bcol0 = nt * 128;

  f32x4 acc[4][4] = {};

  auto stage = [&](int slot, int kt) {
    const int fbase = (kt < 8) ? (d * 256 + kt * 32)
                               : ((DYN - 1 - d) * 256 + (kt - 8) * 32);
    #pragma unroll
    for (int j = 0; j < 2; ++j) {
      int c = j * 256 + t;              // physical 16B chunk index (0..511)
      int cl = c ^ ((c >> 3) & 7);      // logical chunk (involution)
      int r = cl >> 2, kc = cl & 3;     // logical row / k-octet
      const u16* ga = aprep + (size_t)(arow0 + r) * KTOT + kt * 32 + kc * 8;
      const u16* gb = xbf + (size_t)(bcol0 + r) * NF + fbase + kc * 8;
      unsigned lbase = (unsigned)((j * 256 + wave * 64) * 16);
      __builtin_amdgcn_global_load_lds(
          (const __attribute__((address_space(1))) unsigned int*)ga,
          (__attribute__((address_space(3))) unsigned int*)(
              (char*)&As[slot * 4096] + lbase), 16, 0, 0);
      __builtin_amdgcn_global_load_lds(
          (const __attribute__((address_space(1))) unsigned int*)gb,
          (__attribute__((address_space(3))) unsigned int*)(
              (char*)&Bs[slot * 4096] + lbase), 16, 0, 0);
    }
  };

  const int kmask = ((llo >> 1) & 7) << 4;   // thread-constant swizzle mask

  stage(0, 0);
  stage(1, 1);
  // fc fold: overlapped with the in-flight stage loads.
  if (t < 128) {
    int col = bcol0 + t;
    float fs = 0.f;
    #pragma unroll
    for (int i = 0; i < 32; ++i) fs += partial[i * BSN + col];
    fcl[t] = rsqrtf(fs * (1.0f / 4096.0f) + 1e-6f);
  }
  asm volatile("s_waitcnt vmcnt(4)\n\ts_barrier" ::: "memory");

  for (int kt = 0; kt < 16; ++kt) {
    const int slot = kt % 3;
    if (kt < 14) stage((kt + 2) % 3, kt + 2);

    bf16x8 af[4], bq[4];
    #pragma unroll
    for (int m = 0; m < 4; ++m) {
      int rowa = wm * 64 + m * 16 + llo;
      int offa = (rowa * 64 + lhi * 16) ^ kmask;
      af[m] = *reinterpret_cast<const bf16x8*>(
          (const char*)&As[slot * 4096] + offa);
    }
    #pragma unroll
    for (int n = 0; n < 4; ++n) {
      int rowb = wn * 64 + n * 16 + llo;
      int offb = (rowb * 64 + lhi * 16) ^ kmask;
      bq[n] = *reinterpret_cast<const bf16x8*>(
          (const char*)&Bs[slot * 4096] + offb);
    }
    __builtin_amdgcn_s_setprio(1);
    #pragma unroll
    for (int m = 0; m < 4; ++m)
      #pragma unroll
      for (int n = 0; n < 4; ++n)
        acc[m][n] = __builtin_amdgcn_mfma_f32_16x16x32_bf16(
            af[m], bq[n], acc[m][n], 0, 0, 0);
    __builtin_amdgcn_s_setprio(0);

    if (kt < 14) {
      asm volatile("s_waitcnt vmcnt(4)\n\ts_barrier" ::: "memory");
    } else if (kt == 14) {
      asm volatile("s_waitcnt vmcnt(0)\n\ts_barrier" ::: "memory");
    }
  }

  // Epilogue: y = relu(fc[col] * acc + bias[row])
  float fcv[4];
  #pragma unroll
  for (int n = 0; n < 4; ++n) fcv[n] = fcl[wn * 64 + n * 16 + llo];
  #pragma unroll
  for (int m = 0; m < 4; ++m) {
    int row0 = arow0 + wm * 64 + m * 16 + lhi * 4;
    float bv[4];
    #pragma unroll
    for (int r = 0; r < 4; ++r) bv[r] = bias[row0 + r];
    #pragma unroll
    for (int n = 0; n < 4; ++n) {
      int col = bcol0 + wn * 64 + n * 16 + llo;
      #pragma unroll
      for (int r = 0; r < 4; ++r) {
        float v = acc[m][n][r] * fcv[n] + bv[r];
        out[(size_t)(row0 + r) * BSN + col] = fmaxf(v, 0.f);
      }
    }
  }
}

extern "C" void kernel_launch(void* const* d_in, const int* in_sizes, int n_in,
                              void* d_out, int out_size, void* d_ws, size_t ws_size,
                              hipStream_t stream) {
  (void)in_sizes; (void)n_in; (void)out_size; (void)ws_size;
  const float* x    = (const float*)d_in[0];
  const float* rms  = (const float*)d_in[1];
  const float* wu   = (const float*)d_in[2];
  const float* wl   = (const float*)d_in[3];
  const float* bias = (const float*)d_in[4];
  float* out = (float*)d_out;

  char* ws = (char*)d_ws;
  u16* xbf      = (u16*)ws;                      // 32 MiB  (x^T bf16)
  u16* aprep    = (u16*)(ws + 33554432);         // 4 MiB   (folded weights)
  float* partial = (float*)(ws + 37748736);      // 512 KiB (sumsq partials)

  k_prep_w<<<1024, 256, 0, stream>>>(wu, wl, rms, aprep);
  k_transpose<<<dim3(32, 32), 256, 0, stream>>>(x, xbf, partial);
  k_gemm<<<1024, 256, 49664, stream>>>(aprep, xbf, partial, bias, out);
}